// Round 3
// baseline (156.148 us; speedup 1.0000x reference)
//
#include <hip/hip_runtime.h>
#include <hip/hip_bf16.h>
#include <hip/hip_fp16.h>
#include <stdint.h>

// out[e] = sum_d |nodes[r[e]][d] - nodes[c[e]][d]| * w[d] + b[0]
// E = 600000, D = 128, N_OUT = 1.
//
// R1: fp32 gather, 614 MB gathered, 85 us  (~7.2 TB/s effective)
// R2: fp16 table,  307 MB gathered, 42 us  (~7.3 TB/s effective)
// R3: ILP 2->4 loads/thread: neutral. R4: packed fdot2 math: neutral.
//   => byte-proportional wall, not VALU, not MLP. Suspect L2-miss path
//      (table evicted every iter by the 268 MB ws poison; FETCH 132 MB
//      @ 3.1 TB/s on the gather).
// R5: dimension-partitioned gather. The dot is separable over d,
//   so split 128 dims into 8 blocks of 16. tbl2[k][node][16] fp16: each
//   slice = 3.2 MB -> fits one XCD's 4 MB L2. Pin dim-block k to XCD k
//   via blockIdx%8 (measured round-robin mapping). All gather reads become
//   XCD-local L2 hits. Partials [8][E] f32 written nt, reduced in pass 3.
// R6 (this): identical resubmit — R5 bench died on container acquisition
//   (infra), source re-audited: alignment/bounds/ws-budget all OK.

#define D_FEAT 128
#define DBLK   8      // dim blocks (== XCD count)
#define DPB    16     // dims per block

typedef _Float16 h2v __attribute__((ext_vector_type(2)));

// ---- packed abs-diff dot: acc += dot(|a-b|, w) over 2 halves ----
__device__ __forceinline__ float absdot(uint32_t a, uint32_t b, uint32_t w,
                                        float acc)
{
#if __has_builtin(__builtin_amdgcn_fdot2)
    const h2v av = __builtin_bit_cast(h2v, a);
    const h2v bv = __builtin_bit_cast(h2v, b);
    const h2v d  = av - bv;                                   // v_pk_sub_f16
    const uint32_t ad = __builtin_bit_cast(uint32_t, d) & 0x7FFF7FFFu;
    return __builtin_amdgcn_fdot2(__builtin_bit_cast(h2v, ad),
                                  __builtin_bit_cast(h2v, w), acc, false);
#else
    const float2 x = __half22float2(__builtin_bit_cast(__half2, a));
    const float2 y = __half22float2(__builtin_bit_cast(__half2, b));
    const float2 ww = __half22float2(__builtin_bit_cast(__half2, w));
    return acc + fabsf(x.x - y.x) * ww.x + fabsf(x.y - y.y) * ww.y;
#endif
}

// ---- pass 1: fp32 -> fp16 convert + transpose to [k][node][16] ----
// Thread t: node n = t>>3, dim-block k = t&7. Reads 16 f32 (64B contiguous,
// wave covers 8 full rows coalesced). Writes 32B to slice k (8-lane groups
// write 256B contiguous segments).
__global__ __launch_bounds__(256) void convert_transpose(
    const float* __restrict__ src, __half* __restrict__ tbl2,
    const float* __restrict__ w, __half* __restrict__ wh, int n_nodes)
{
    // 16 threads of block 0 convert w (128 f32 -> 128 f16, linear order)
    if (blockIdx.x == 0 && threadIdx.x < (D_FEAT / 8)) {
        const float4* s = (const float4*)w + 2 * (size_t)threadIdx.x;
        const float4 a = s[0];
        const float4 c = s[1];
        float4 packed;
        ((__half2*)&packed)[0] = __floats2half2_rn(a.x, a.y);
        ((__half2*)&packed)[1] = __floats2half2_rn(a.z, a.w);
        ((__half2*)&packed)[2] = __floats2half2_rn(c.x, c.y);
        ((__half2*)&packed)[3] = __floats2half2_rn(c.z, c.w);
        ((float4*)wh)[threadIdx.x] = packed;
    }

    const int t = blockIdx.x * blockDim.x + threadIdx.x;
    const int n = t >> 3;
    const int k = t & (DBLK - 1);
    if (n >= n_nodes) return;

    const float4* s = (const float4*)(src + (size_t)n * D_FEAT + k * DPB);
    const float4 f0 = s[0], f1 = s[1], f2 = s[2], f3 = s[3];
    uint4 p0, p1;
    __half2* h0 = (__half2*)&p0;
    __half2* h1 = (__half2*)&p1;
    h0[0] = __floats2half2_rn(f0.x, f0.y);
    h0[1] = __floats2half2_rn(f0.z, f0.w);
    h0[2] = __floats2half2_rn(f1.x, f1.y);
    h0[3] = __floats2half2_rn(f1.z, f1.w);
    h1[0] = __floats2half2_rn(f2.x, f2.y);
    h1[1] = __floats2half2_rn(f2.z, f2.w);
    h1[2] = __floats2half2_rn(f3.x, f3.y);
    h1[3] = __floats2half2_rn(f3.z, f3.w);

    uint4* d = (uint4*)(tbl2 + ((size_t)k * n_nodes + n) * DPB);
    d[0] = p0;
    d[1] = p1;
}

// ---- pass 2: per-dim-block gather. blockIdx%8 = dim block = XCD. ----
// 1 thread per (edge, dblk): 4 independent 16B gathers, all within the
// XCD-local 3.2 MB slice. Index loads + partial stores are non-temporal
// so the streams don't evict the slice from L2.
__global__ __launch_bounds__(256) void gather_partial(
    const __half* __restrict__ tbl2,
    const __half* __restrict__ wh,
    const int*   __restrict__ r_idx,
    const int*   __restrict__ c_idx,
    float*       __restrict__ partial,   // [DBLK][E] f32
    int n_edges, int n_nodes)
{
    const int dblk  = blockIdx.x & (DBLK - 1);
    const int chunk = blockIdx.x >> 3;
    const int e = chunk * blockDim.x + threadIdx.x;
    if (e >= n_edges) return;

    const int r = __builtin_nontemporal_load(r_idx + e);
    const int c = __builtin_nontemporal_load(c_idx + e);

    const __half* base = tbl2 + (size_t)dblk * n_nodes * DPB;
    const uint4* rp = (const uint4*)(base + (size_t)r * DPB);
    const uint4* cp = (const uint4*)(base + (size_t)c * DPB);

    // 4 independent 16B gather loads (32B per endpoint)
    const uint4 a0 = rp[0];
    const uint4 a1 = rp[1];
    const uint4 b0 = cp[0];
    const uint4 b1 = cp[1];

    const uint4* wp = (const uint4*)(wh + dblk * DPB);
    const uint4 w0 = wp[0];
    const uint4 w1 = wp[1];

    float s0 = 0.f, s1 = 0.f;
    s0 = absdot(a0.x, b0.x, w0.x, s0);
    s0 = absdot(a0.y, b0.y, w0.y, s0);
    s0 = absdot(a0.z, b0.z, w0.z, s0);
    s0 = absdot(a0.w, b0.w, w0.w, s0);
    s1 = absdot(a1.x, b1.x, w1.x, s1);
    s1 = absdot(a1.y, b1.y, w1.y, s1);
    s1 = absdot(a1.z, b1.z, w1.z, s1);
    s1 = absdot(a1.w, b1.w, w1.w, s1);

    __builtin_nontemporal_store(s0 + s1,
                                partial + (size_t)dblk * n_edges + e);
}

// ---- pass 3: out[e] = b + sum_k partial[k][e], 4 edges/thread ----
__global__ __launch_bounds__(256) void reduce_partial(
    const float* __restrict__ partial, const float* __restrict__ b,
    float* __restrict__ out, int n_edges)
{
    const int q  = blockIdx.x * blockDim.x + threadIdx.x;
    const int e0 = q * 4;
    if (e0 >= n_edges) return;

    if (e0 + 4 <= n_edges) {
        const float bb = b[0];
        float4 acc = make_float4(bb, bb, bb, bb);
        #pragma unroll
        for (int k = 0; k < DBLK; ++k) {
            const float4 p =
                *(const float4*)(partial + (size_t)k * n_edges + e0);
            acc.x += p.x; acc.y += p.y; acc.z += p.z; acc.w += p.w;
        }
        *(float4*)(out + e0) = acc;
    } else {
        for (int e = e0; e < n_edges; ++e) {
            float acc = b[0];
            for (int k = 0; k < DBLK; ++k)
                acc += partial[(size_t)k * n_edges + e];
            out[e] = acc;
        }
    }
}

// ---- fallback: direct fp32 gather (R1 path), if ws too small ----
__global__ __launch_bounds__(256) void gather_edges_f32(
    const float* __restrict__ nodes,
    const int*   __restrict__ r_idx,
    const int*   __restrict__ c_idx,
    const float* __restrict__ w,
    const float* __restrict__ b,
    float*       __restrict__ out,
    int n_edges)
{
    const int tid  = blockIdx.x * blockDim.x + threadIdx.x;
    const int lane = tid & 31;
    const int edge = tid >> 5;
    if (edge >= n_edges) return;

    const int r = r_idx[edge];
    const int c = c_idx[edge];

    const float4 wv = ((const float4*)w)[lane];
    const float4 av = ((const float4*)(nodes + (size_t)r * D_FEAT))[lane];
    const float4 bv = ((const float4*)(nodes + (size_t)c * D_FEAT))[lane];

    float s = fabsf(av.x - bv.x) * wv.x
            + fabsf(av.y - bv.y) * wv.y
            + fabsf(av.z - bv.z) * wv.z
            + fabsf(av.w - bv.w) * wv.w;

    #pragma unroll
    for (int off = 16; off > 0; off >>= 1)
        s += __shfl_xor(s, off, 64);

    if (lane == 0)
        out[edge] = s + b[0];
}

extern "C" void kernel_launch(void* const* d_in, const int* in_sizes, int n_in,
                              void* d_out, int out_size, void* d_ws, size_t ws_size,
                              hipStream_t stream) {
    const float* nodes = (const float*)d_in[0];   // [N_NODES, 128] f32
    const int*   r_idx = (const int*)d_in[1];     // [E] int
    const int*   c_idx = (const int*)d_in[2];     // [E] int
    const float* w     = (const float*)d_in[3];   // [128, 1] f32
    const float* b     = (const float*)d_in[4];   // [1] f32
    float*       out   = (float*)d_out;           // [E] f32

    const int n_edges   = in_sizes[1];
    const int n_nodes_f = in_sizes[0];            // n_nodes * 128 floats
    const int n_nodes   = n_nodes_f / D_FEAT;

    const size_t tbl_bytes  = (size_t)n_nodes_f * sizeof(__half); // 25.6 MB
    const size_t wh_bytes   = (size_t)D_FEAT * sizeof(__half);    // 256 B
    const size_t part_bytes = (size_t)DBLK * n_edges * sizeof(float); // 19.2 MB

    if (ws_size >= tbl_bytes + wh_bytes + part_bytes &&
        (n_nodes_f % D_FEAT) == 0) {
        __half* tbl2    = (__half*)d_ws;
        __half* wh      = tbl2 + (size_t)n_nodes_f;
        float*  partial = (float*)((char*)d_ws + tbl_bytes + wh_bytes);

        // pass 1: convert + transpose (grid over node x dim-block)
        {
            const int total = n_nodes * DBLK;
            const int block = 256;
            const int grid  = (total + block - 1) / block;
            convert_transpose<<<grid, block, 0, stream>>>(
                nodes, tbl2, w, wh, n_nodes);
        }
        // pass 2: XCD-partitioned gather
        {
            const int block  = 256;
            const int chunks = (n_edges + block - 1) / block;
            const int grid   = chunks * DBLK;   // blockIdx%8 = dim block
            gather_partial<<<grid, block, 0, stream>>>(
                tbl2, wh, r_idx, c_idx, partial, n_edges, n_nodes);
        }
        // pass 3: reduce partials
        {
            const int block = 256;
            const int quads = (n_edges + 3) / 4;
            const int grid  = (quads + block - 1) / block;
            reduce_partial<<<grid, block, 0, stream>>>(
                partial, b, out, n_edges);
        }
    } else {
        const int block = 256;
        const int grid  = (int)(((long long)n_edges * 32 + block - 1) / block);
        gather_edges_f32<<<grid, block, 0, stream>>>(
            nodes, r_idx, c_idx, w, b, out, n_edges);
    }
}